// Round 2
// baseline (244.166 us; speedup 1.0000x reference)
//
#include <hip/hip_runtime.h>

// ONN conv2d: B=16, Cin=128, H=W=32, Cout=256, k=3 (pad=1, stride=1)
// N = B*H*W = 16384 positions, D = Cin*k*k = 1152, VEC=64, R=18 chunks, M=256
// out[n,m] = sum_r ( dot_{c=0..63}( x[n, 64r+c], wq[64r+c, m] ) >= 0 ? 1 : 0 )
// wq = clamp(round_half_even(w * scale), -7, 7), scale = 15/(max(w)-min(w)+1e-9)
//
// NUMERICS CONTRACT (matches numpy fp32 transcription of the reference):
//  - scale computed entirely in fp32: fl32(15 / fl32(fl32(max-min) + 1e-9f))
//  - quant: rintf(fl32(w*scale)) -- round half to even, fp32 product
//  - dot: sequential fp32 accumulation, c ascending, SEPARATE mul/add
//    roundings (__fmul_rn/__fadd_rn -- no FMA contraction), matching
//    np.einsum's axpy-over-m / ascending-c accumulation order.

#define N_TOTAL 16384
#define M_TOTAL 256
#define D_TOTAL 1152
#define W_ELEMS 294912   // 256*128*3*3 = 1152*256

__global__ __launch_bounds__(256) void k_minmax(const float* __restrict__ w,
                                                float* __restrict__ pmin,
                                                float* __restrict__ pmax) {
    int tid = blockIdx.x * blockDim.x + threadIdx.x;
    float vmin = 1e30f, vmax = -1e30f;
    for (int i = tid; i < W_ELEMS; i += gridDim.x * blockDim.x) {
        float v = w[i];
        vmin = fminf(vmin, v);
        vmax = fmaxf(vmax, v);
    }
    #pragma unroll
    for (int off = 32; off > 0; off >>= 1) {
        vmin = fminf(vmin, __shfl_down(vmin, off, 64));
        vmax = fmaxf(vmax, __shfl_down(vmax, off, 64));
    }
    __shared__ float smin[4], smax[4];
    int wave = threadIdx.x >> 6;
    if ((threadIdx.x & 63) == 0) { smin[wave] = vmin; smax[wave] = vmax; }
    __syncthreads();
    if (threadIdx.x == 0) {
        #pragma unroll
        for (int i = 1; i < 4; i++) {
            vmin = fminf(vmin, smin[i]);
            vmax = fmaxf(vmax, smax[i]);
        }
        pmin[blockIdx.x] = vmin;
        pmax[blockIdx.x] = vmax;
    }
}

__global__ void k_scale(const float* __restrict__ pmin, const float* __restrict__ pmax,
                        float* __restrict__ scale) {
    float vmin = pmin[threadIdx.x];
    float vmax = pmax[threadIdx.x];
    #pragma unroll
    for (int off = 32; off > 0; off >>= 1) {
        vmin = fminf(vmin, __shfl_down(vmin, off, 64));
        vmax = fmaxf(vmax, __shfl_down(vmax, off, 64));
    }
    if (threadIdx.x == 0) {
        // all-fp32, matching numpy: (max - min) + 1e-9f, then 15 / x
        float t = __fadd_rn(__fsub_rn(vmax, vmin), 1e-9f);
        *scale = __fdiv_rn(15.0f, t);
    }
}

// quantize + transpose: wq_t[d*256 + m] = clamp(rintf(w[m*1152+d]*scale), -7, 7)
__global__ __launch_bounds__(256) void k_quant(const float* __restrict__ w,
                                               const float* __restrict__ scale,
                                               float* __restrict__ wq) {
    int idx = blockIdx.x * 256 + threadIdx.x;   // exact grid: 1152*256
    float s = *scale;
    float q = rintf(__fmul_rn(w[idx], s));      // fp32 product, round half-even
    q = q > 7.0f ? 7.0f : (q < -7.0f ? -7.0f : q);
    int m = idx / D_TOTAL;
    int d = idx - m * D_TOTAL;
    wq[d * M_TOTAL + m] = q;
}

// Main kernel: tile 64 n-positions x 64 m-outputs per block, 256 threads,
// 4x4 micro-tile per thread, fp32 sequential accumulation per 64-chunk.
__global__ __launch_bounds__(256) void k_main(const float* __restrict__ inp,
                                              const float* __restrict__ wq,
                                              float* __restrict__ out) {
    __shared__ float xs[64][64];    // [c][nn]
    __shared__ float wsm[64][64];   // [c][mm]

    const int tid = threadIdx.x;
    const int tm = tid & 15;        // micro col group
    const int tn = tid >> 4;        // micro row group
    const int n0 = blockIdx.x * 64; // 64 consecutive spatial positions (2 image rows)
    const int m0 = blockIdx.y * 64;
    const int b  = n0 >> 10;        // image index (1024 positions per image)
    const int p0 = n0 & 1023;       // position base within image

    const float* __restrict__ inpb = inp + (size_t)b * (128 * 32 * 32);

    int counts[4][4] = {};

    const int nn_s = tid & 63;      // staging nn/mm (lane id)
    const int c_s  = tid >> 6;      // staging c base (0..3), steps by 4

    for (int r = 0; r < 18; ++r) {
        // ---- stage x (im2col) and w tiles into LDS ----
        #pragma unroll
        for (int i = 0; i < 16; ++i) {
            int c = c_s + i * 4;
            int d = r * 64 + c;
            int cin = d / 9;
            int rem = d - cin * 9;
            int kh = rem / 3;
            int kw = rem - kh * 3;
            int n = p0 + nn_s;
            int yy = (n >> 5) + kh - 1;
            int xx = (n & 31) + kw - 1;
            float v = 0.0f;
            if ((unsigned)yy < 32u && (unsigned)xx < 32u)
                v = inpb[(cin * 32 + yy) * 32 + xx];
            xs[c][nn_s] = v;
            wsm[c][nn_s] = wq[d * M_TOTAL + m0 + nn_s];
        }
        __syncthreads();

        // ---- fp32 dot over the 64-chunk: sequential, c ascending,
        //      separate mul/add roundings (NO fma) ----
        float acc[4][4] = {};
        #pragma unroll 4
        for (int c = 0; c < 64; ++c) {
            float4 xv = *(const float4*)&xs[c][tn * 4];
            float4 wv = *(const float4*)&wsm[c][tm * 4];
            float xd[4] = {xv.x, xv.y, xv.z, xv.w};
            float wd[4] = {wv.x, wv.y, wv.z, wv.w};
            #pragma unroll
            for (int i = 0; i < 4; ++i)
                #pragma unroll
                for (int j = 0; j < 4; ++j)
                    acc[i][j] = __fadd_rn(acc[i][j], __fmul_rn(xd[i], wd[j]));
        }

        // ---- binarize (s < 0 -> 0 else 1) and count; clip can't change sign ----
        #pragma unroll
        for (int i = 0; i < 4; ++i)
            #pragma unroll
            for (int j = 0; j < 4; ++j)
                counts[i][j] += (acc[i][j] >= 0.0f) ? 1 : 0;

        __syncthreads();
    }

    // ---- epilogue: out[b, m, p] fp32, float4 over consecutive positions ----
    #pragma unroll
    for (int j = 0; j < 4; ++j) {
        int m = m0 + tm * 4 + j;
        float4 o;
        o.x = (float)counts[0][j];
        o.y = (float)counts[1][j];
        o.z = (float)counts[2][j];
        o.w = (float)counts[3][j];
        *(float4*)&out[((size_t)(b * 256 + m) << 10) + p0 + tn * 4] = o;
    }
}

extern "C" void kernel_launch(void* const* d_in, const int* in_sizes, int n_in,
                              void* d_out, int out_size, void* d_ws, size_t ws_size,
                              hipStream_t stream) {
    const float* inp    = (const float*)d_in[0];   // [16,128,32,32]
    const float* weight = (const float*)d_in[1];   // [256,128,3,3]
    float* out = (float*)d_out;                    // [16,256,32,32]

    char* ws = (char*)d_ws;
    float* pmin  = (float*)ws;               // 64 floats
    float* pmax  = (float*)(ws + 256);       // 64 floats
    float* scale = (float*)(ws + 512);       // 1 float
    float* wq    = (float*)(ws + 1024);      // 1152*256 floats (~1.18 MB)

    k_minmax<<<64, 256, 0, stream>>>(weight, pmin, pmax);
    k_scale<<<1, 64, 0, stream>>>(pmin, pmax, scale);
    k_quant<<<D_TOTAL, 256, 0, stream>>>(weight, scale, wq);

    dim3 grid(N_TOTAL / 64, M_TOTAL / 64);   // 256 x 4 = 1024 blocks
    k_main<<<grid, 256, 0, stream>>>(inp, wq, out);
}